// Round 5
// baseline (124.339 us; speedup 1.0000x reference)
//
#include <hip/hip_runtime.h>
#include <hip/hip_bf16.h>
#include <math.h>

#define NPAIR 4096       // N = B*S
#define D 128
#define TWO_N 8192

typedef short bf16x8 __attribute__((ext_vector_type(8)));
typedef float f32x4 __attribute__((ext_vector_type(4)));

__device__ inline unsigned short f2bf(float x) {
    union { float f; unsigned u; } v; v.f = x;
    unsigned u = v.u;
    unsigned r = u + 0x7fffu + ((u >> 16) & 1u);   // round-to-nearest-even
    return (unsigned short)(r >> 16);
}

// 1024 blocks x 256 threads; wave w handles pair-row k = blockIdx*4 + w.
// Also zero-inits rowsum (simexp accumulates atomically) and out[0].
__global__ __launch_bounds__(256) void norm_kernel(const float* __restrict__ zi,
                                                   const float* __restrict__ zj,
                                                   unsigned int* __restrict__ Rb,
                                                   float* __restrict__ pos,
                                                   float* __restrict__ rowsum,
                                                   float* __restrict__ out) {
    if (threadIdx.x < 8) rowsum[blockIdx.x * 8 + threadIdx.x] = 0.f;
    if (blockIdx.x == 0 && threadIdx.x == 8) out[0] = 0.f;
    int k = blockIdx.x * 4 + (threadIdx.x >> 6);
    int t = threadIdx.x & 63;                 // 2 elems each
    const float2 a = *(const float2*)(zi + k * D + 2 * t);
    const float2 b = *(const float2*)(zj + k * D + 2 * t);
    float si = a.x * a.x + a.y * a.y;
    float sj = b.x * b.x + b.y * b.y;
    float dt = a.x * b.x + a.y * b.y;
    #pragma unroll
    for (int m = 1; m < 64; m <<= 1) {
        si += __shfl_xor(si, m, 64);
        sj += __shfl_xor(sj, m, 64);
        dt += __shfl_xor(dt, m, 64);
    }
    float ii = 1.0f / fmaxf(sqrtf(si), 1e-12f);
    float ij = 1.0f / fmaxf(sqrtf(sj), 1e-12f);
    unsigned short b0 = f2bf(a.x * ii), b1 = f2bf(a.y * ii);
    Rb[k * (D / 2) + t] = (unsigned)b0 | ((unsigned)b1 << 16);
    b0 = f2bf(b.x * ij); b1 = f2bf(b.y * ij);
    Rb[(k + NPAIR) * (D / 2) + t] = (unsigned)b0 | ((unsigned)b1 << 16);
    if (t == 0) pos[k] = dt * ii * ij;
}

// Symmetric-triangle version: 64x64 2D grid, only bi <= bj tiles live (2080).
// One 128x128 tile per block, 4 waves = 4 quadrants. No LDS, no barriers:
// A and B fragments load global->VGPR (Rb is L2-resident). Off-diag tiles
// contribute row-sums (stripe bi) AND col-sums (stripe bj, = row-sums by
// symmetry); diagonal tiles contribute row-sums only, excluding ro==co.
// Accumulate into rowsum[] with exec-masked atomicAdd.
__global__ __launch_bounds__(256, 2) void simexp_kernel(const uint4* __restrict__ Rb,
                                                        float* __restrict__ rowsum) {
    const int bi = blockIdx.y, bj = blockIdx.x;
    if (bj < bi) return;
    const int tid = threadIdx.x;
    const int wave = tid >> 6, lane = tid & 63;
    const int rp = lane & 15, q = lane >> 4;
    const int wr = (wave & 1) * 64;      // row quadrant
    const int wc = (wave >> 1) * 64;     // col quadrant

    // A fragments: row = bi*128 + wr + rt*16 + rp, chunk = kt*4 + q
    bf16x8 afr[4][4];                    // [kt][rt]
    {
        const uint4* Ab = Rb + (bi * 128 + wr + rp) * 16;
        #pragma unroll
        for (int kt = 0; kt < 4; ++kt)
            #pragma unroll
            for (int rt = 0; rt < 4; ++rt)
                afr[kt][rt] = *(const bf16x8*)&Ab[rt * 256 + kt * 4 + q];
    }

    const uint4* Bb = Rb + (bj * 128 + wc + rp) * 16;
    f32x4 acc[4][4] = {};
    #pragma unroll
    for (int kt = 0; kt < 4; ++kt) {
        bf16x8 bfr[4];
        #pragma unroll
        for (int ct = 0; ct < 4; ++ct)
            bfr[ct] = *(const bf16x8*)&Bb[ct * 256 + kt * 4 + q];
        #pragma unroll
        for (int rt = 0; rt < 4; ++rt)
            #pragma unroll
            for (int ct = 0; ct < 4; ++ct)
                acc[rt][ct] = __builtin_amdgcn_mfma_f32_16x16x32_bf16(
                    afr[kt][rt], bfr[ct], acc[rt][ct], 0, 0, 0);
    }

    // D layout: col = wc + ct*16 + rp, row = wr + rt*16 + q*4 + r
    float rsum[16];
    float csum[4] = {0.f, 0.f, 0.f, 0.f};
    if (bi == bj) {                      // diagonal tile: rows only, skip ro==co
        #pragma unroll
        for (int rt = 0; rt < 4; ++rt)
            #pragma unroll
            for (int r = 0; r < 4; ++r) {
                int ro = wr + rt * 16 + q * 4 + r;
                float s = 0.f;
                #pragma unroll
                for (int ct = 0; ct < 4; ++ct) {
                    int co = wc + ct * 16 + rp;
                    float x = acc[rt][ct][r];
                    float e = __expf(x + x);
                    s += (ro == co) ? 0.f : e;
                }
                rsum[rt * 4 + r] = s;
            }
    } else {
        #pragma unroll
        for (int rt = 0; rt < 4; ++rt)
            #pragma unroll
            for (int r = 0; r < 4; ++r) {
                float s = 0.f;
                #pragma unroll
                for (int ct = 0; ct < 4; ++ct) {
                    float x = acc[rt][ct][r];
                    float e = __expf(x + x);
                    s += e;
                    csum[ct] += e;
                }
                rsum[rt * 4 + r] = s;
            }
    }

    // Row-sums: reduce across the 16 rp lanes; rp==0 lanes (q=0..3) hold
    // 16 distinct rows each.
    #pragma unroll
    for (int i = 0; i < 16; ++i) {
        float v = rsum[i];
        v += __shfl_xor(v, 1, 64);
        v += __shfl_xor(v, 2, 64);
        v += __shfl_xor(v, 4, 64);
        v += __shfl_xor(v, 8, 64);
        if (rp == 0)
            atomicAdd(&rowsum[bi * 128 + wr + (i >> 2) * 16 + q * 4 + (i & 3)], v);
    }
    // Col-sums (off-diagonal only): reduce across the 4 q lanes; q==0 lanes
    // (rp=0..15) hold 4 distinct cols each.
    if (bi != bj) {
        #pragma unroll
        for (int ct = 0; ct < 4; ++ct) {
            float v = csum[ct];
            v += __shfl_xor(v, 16, 64);
            v += __shfl_xor(v, 32, 64);
            if (q == 0)
                atomicAdd(&rowsum[bj * 128 + wc + ct * 16 + rp], v);
        }
    }
}

// 16 blocks x 256 threads; each thread does 2 rows; one atomicAdd per block.
__global__ __launch_bounds__(256) void finalize_kernel(const float* __restrict__ rowsum,
                                                       const float* __restrict__ pos,
                                                       float* __restrict__ out) {
    __shared__ float red[4];
    int tid = threadIdx.x;
    float local = 0.f;
    #pragma unroll
    for (int i = 0; i < 2; ++i) {
        int k = blockIdx.x * 512 + i * 256 + tid;
        float ps = pos[k & (NPAIR - 1)];
        float p2 = ps + ps;
        local += logf(rowsum[k] + __expf(p2)) - p2;
    }
    #pragma unroll
    for (int m = 1; m < 64; m <<= 1) local += __shfl_xor(local, m, 64);
    if ((tid & 63) == 0) red[tid >> 6] = local;
    __syncthreads();
    if (tid == 0) {
        float s = red[0] + red[1] + red[2] + red[3];
        atomicAdd(out, s * (1.0f / (float)TWO_N));
    }
}

extern "C" void kernel_launch(void* const* d_in, const int* in_sizes, int n_in,
                              void* d_out, int out_size, void* d_ws, size_t ws_size,
                              hipStream_t stream) {
    const float* zi = (const float*)d_in[0];
    const float* zj = (const float*)d_in[1];
    char* ws = (char*)d_ws;
    unsigned int* Rb = (unsigned int*)ws;                           // 2 MB bf16 rows
    float* rowsum = (float*)(ws + 2 * 1024 * 1024);                 // 32 KB
    float* pos = (float*)(ws + 2 * 1024 * 1024 + 32 * 1024);        // 16 KB

    norm_kernel<<<NPAIR / 4, 256, 0, stream>>>(zi, zj, Rb, pos, rowsum, (float*)d_out);
    simexp_kernel<<<dim3(64, 64), 256, 0, stream>>>((const uint4*)Rb, rowsum);
    finalize_kernel<<<16, 256, 0, stream>>>(rowsum, pos, (float*)d_out);
}

// Round 6
// 97.246 us; speedup vs baseline: 1.2786x; 1.2786x over previous
//
#include <hip/hip_runtime.h>
#include <hip/hip_bf16.h>
#include <math.h>

#define NPAIR 4096       // N = B*S
#define D 128
#define TWO_N 8192
#define NJC 8            // col-slab splits; each block covers 1024 cols
#define NPART (NJC * 2)  // two col-half waves per block store separately
// Rb rows are pre-scaled by ALPHA = sqrt(2*log2(e)) so the MFMA accumulator
// is exactly 2*log2(e)*sim, and exp(2*sim) == exp2(acc): bare v_exp_f32.
#define ALPHA 1.6986436f

typedef short bf16x8 __attribute__((ext_vector_type(8)));
typedef float f32x4 __attribute__((ext_vector_type(4)));

__device__ inline unsigned short f2bf(float x) {
    union { float f; unsigned u; } v; v.f = x;
    unsigned u = v.u;
    unsigned r = u + 0x7fffu + ((u >> 16) & 1u);   // round-to-nearest-even
    return (unsigned short)(r >> 16);
}

// 1024 blocks x 256 threads; wave w handles pair-row k = blockIdx*4 + w.
// Emits ALPHA-scaled bf16 rows; pos[] stays exact fp32. Zero-inits out[0].
__global__ __launch_bounds__(256) void norm_kernel(const float* __restrict__ zi,
                                                   const float* __restrict__ zj,
                                                   unsigned int* __restrict__ Rb,
                                                   float* __restrict__ pos,
                                                   float* __restrict__ out) {
    if (blockIdx.x == 0 && threadIdx.x == 0) out[0] = 0.f;
    int k = blockIdx.x * 4 + (threadIdx.x >> 6);
    int t = threadIdx.x & 63;                 // 2 elems each
    const float2 a = *(const float2*)(zi + k * D + 2 * t);
    const float2 b = *(const float2*)(zj + k * D + 2 * t);
    float si = a.x * a.x + a.y * a.y;
    float sj = b.x * b.x + b.y * b.y;
    float dt = a.x * b.x + a.y * b.y;
    #pragma unroll
    for (int m = 1; m < 64; m <<= 1) {
        si += __shfl_xor(si, m, 64);
        sj += __shfl_xor(sj, m, 64);
        dt += __shfl_xor(dt, m, 64);
    }
    float ii = 1.0f / fmaxf(sqrtf(si), 1e-12f);
    float ij = 1.0f / fmaxf(sqrtf(sj), 1e-12f);
    if (t == 0) pos[k] = dt * ii * ij;        // exact (unscaled) positive sim
    ii *= ALPHA; ij *= ALPHA;
    unsigned short b0 = f2bf(a.x * ii), b1 = f2bf(a.y * ii);
    Rb[k * (D / 2) + t] = (unsigned)b0 | ((unsigned)b1 << 16);
    b0 = f2bf(b.x * ij); b1 = f2bf(b.y * ij);
    Rb[(k + NPAIR) * (D / 2) + t] = (unsigned)b0 | ((unsigned)b1 << 16);
}

// 512 blocks: bi = b>>3 (128-row stripe), jc = b&7 (1024-col slab as 16
// jt-tiles of 64 cols). NO LDS, NO BARRIERS: A fragments resident in VGPRs;
// B fragments global->VGPR, register double-buffered one jt ahead so next-jt
// loads stay in flight through current-jt compute (per-register vmcnt).
// Wave quadrants: 64 rows x 32 cols. Row-sum partials in 16 regs/lane; one
// shuffle-reduce + plain store per block into 16 race-free slabs.
__global__ __launch_bounds__(256, 2) void simexp_kernel(const uint4* __restrict__ Rb,
                                                        float* __restrict__ rspart) {
    const int bi = blockIdx.x >> 3, jc = blockIdx.x & 7;
    const int tid = threadIdx.x;
    const int wave = tid >> 6, lane = tid & 63;
    const int rp = lane & 15, q = lane >> 4;
    const int wr = (wave & 1) * 64;      // row quadrant (64 rows)
    const int wc = (wave >> 1) * 32;     // col half of the 64-col jt tile

    // A fragments: row = bi*128 + wr + rt*16 + rp, chunk = kt*4 + q
    bf16x8 afr[4][4];                    // [kt][rt]
    {
        const uint4* Ab = Rb + (bi * 128 + wr + rp) * 16;
        #pragma unroll
        for (int kt = 0; kt < 4; ++kt)
            #pragma unroll
            for (int rt = 0; rt < 4; ++rt)
                afr[kt][rt] = *(const bf16x8*)&Ab[rt * 256 + kt * 4 + q];
    }

    // B fragment lane base: row = jc*1024 + jt*64 + wc + ct*16 + rp, chunk kt*4+q
    // index = row*16 + kt*4 + q = base + jt*1024 + ct*256 + kt*4
    const uint4* Bb = Rb + (jc * 1024 + wc + rp) * 16 + q;

    bf16x8 bfr[2][4][2];                 // [buf][kt][ct]
    #pragma unroll
    for (int kt = 0; kt < 4; ++kt)
        #pragma unroll
        for (int ct = 0; ct < 2; ++ct)
            bfr[0][kt][ct] = *(const bf16x8*)&Bb[ct * 256 + kt * 4];

    float rs[16];
    #pragma unroll
    for (int i = 0; i < 16; ++i) rs[i] = 0.f;

    const int diagoff = bi * 128 - jc * 1024;  // stripe start in slab-local cols

    #pragma unroll
    for (int jt = 0; jt < 16; ++jt) {
        const int cur = jt & 1, nxt = cur ^ 1;
        if (jt < 15) {                   // prefetch jt+1 into the other buffer
            #pragma unroll
            for (int kt = 0; kt < 4; ++kt)
                #pragma unroll
                for (int ct = 0; ct < 2; ++ct)
                    bfr[nxt][kt][ct] =
                        *(const bf16x8*)&Bb[(jt + 1) * 1024 + ct * 256 + kt * 4];
        }

        f32x4 acc[4][2] = {};
        #pragma unroll
        for (int kt = 0; kt < 4; ++kt)
            #pragma unroll
            for (int rt = 0; rt < 4; ++rt)
                #pragma unroll
                for (int ct = 0; ct < 2; ++ct)
                    acc[rt][ct] = __builtin_amdgcn_mfma_f32_16x16x32_bf16(
                        afr[kt][rt], bfr[cur][kt][ct], acc[rt][ct], 0, 0, 0);

        // D layout: col = wc + ct*16 + rp, row = wr + rt*16 + q*4 + r
        if ((unsigned)(jt * 64 - diagoff) < 128u) {   // tile touches the diagonal
            #pragma unroll
            for (int rt = 0; rt < 4; ++rt)
                #pragma unroll
                for (int r = 0; r < 4; ++r) {
                    int ro = wr + rt * 16 + q * 4 + r;          // stripe-local row
                    float s = 0.f;
                    #pragma unroll
                    for (int ct = 0; ct < 2; ++ct) {
                        int co = jt * 64 - diagoff + wc + ct * 16 + rp;
                        float e = exp2f(acc[rt][ct][r]);
                        s += (ro == co) ? 0.f : e;
                    }
                    rs[rt * 4 + r] += s;
                }
        } else {
            #pragma unroll
            for (int rt = 0; rt < 4; ++rt)
                #pragma unroll
                for (int r = 0; r < 4; ++r) {
                    float s = 0.f;
                    #pragma unroll
                    for (int ct = 0; ct < 2; ++ct)
                        s += exp2f(acc[rt][ct][r]);
                    rs[rt * 4 + r] += s;
                }
        }
    }

    // Once per block: reduce each reg across the 16 rp lanes, store.
    #pragma unroll
    for (int i = 0; i < 16; ++i) {
        float v = rs[i];
        v += __shfl_xor(v, 1, 64);
        v += __shfl_xor(v, 2, 64);
        v += __shfl_xor(v, 4, 64);
        v += __shfl_xor(v, 8, 64);
        rs[i] = v;
    }
    if (rp == 0) {
        const int slab = jc * 2 + (wave >> 1);    // col-half gets own slab
        const int rowb = bi * 128 + wr + q * 4;
        #pragma unroll
        for (int i = 0; i < 16; ++i)
            rspart[slab * TWO_N + rowb + (i >> 2) * 16 + (i & 3)] = rs[i];
    }
}

// 16 blocks x 256 threads; each thread does 2 rows; one atomicAdd per block.
__global__ __launch_bounds__(256) void finalize_kernel(const float* __restrict__ rspart,
                                                       const float* __restrict__ pos,
                                                       float* __restrict__ out) {
    __shared__ float red[4];
    int tid = threadIdx.x;
    float local = 0.f;
    #pragma unroll
    for (int i = 0; i < 2; ++i) {
        int k = blockIdx.x * 512 + i * 256 + tid;
        float rsum = 0.f;
        #pragma unroll
        for (int p = 0; p < NPART; ++p) rsum += rspart[p * TWO_N + k];
        float ps = pos[k & (NPAIR - 1)];
        float p2 = ps + ps;
        local += logf(rsum + __expf(p2)) - p2;
    }
    #pragma unroll
    for (int m = 1; m < 64; m <<= 1) local += __shfl_xor(local, m, 64);
    if ((tid & 63) == 0) red[tid >> 6] = local;
    __syncthreads();
    if (tid == 0) {
        float s = red[0] + red[1] + red[2] + red[3];
        atomicAdd(out, s * (1.0f / (float)TWO_N));
    }
}

extern "C" void kernel_launch(void* const* d_in, const int* in_sizes, int n_in,
                              void* d_out, int out_size, void* d_ws, size_t ws_size,
                              hipStream_t stream) {
    const float* zi = (const float*)d_in[0];
    const float* zj = (const float*)d_in[1];
    char* ws = (char*)d_ws;
    unsigned int* Rb = (unsigned int*)ws;                           // 2 MB bf16 rows
    float* rspart = (float*)(ws + 2 * 1024 * 1024);                 // 16*8192*4 = 512 KB
    float* pos = (float*)(ws + 2 * 1024 * 1024 + 512 * 1024);       // 16 KB

    norm_kernel<<<NPAIR / 4, 256, 0, stream>>>(zi, zj, Rb, pos, (float*)d_out);
    simexp_kernel<<<64 * NJC, 256, 0, stream>>>((const uint4*)Rb, rspart);
    finalize_kernel<<<16, 256, 0, stream>>>(rspart, pos, (float*)d_out);
}